// Round 7
// baseline (566.474 us; speedup 1.0000x reference)
//
#include <hip/hip_runtime.h>
#include <hip/hip_bf16.h>

#define NR 4096

typedef float f32x4 __attribute__((ext_vector_type(4)));
typedef __bf16 bf16x8 __attribute__((ext_vector_type(8)));

typedef __attribute__((address_space(1))) unsigned int u32_g;
typedef __attribute__((address_space(3))) unsigned int u32_l;

__device__ __forceinline__ void gl_lds16(const void* g, void* l) {
  __builtin_amdgcn_global_load_lds((const u32_g*)g, (u32_l*)l, 16, 0, 0);
}

// =====================================================================
// Staged operand layout (bf16): logical Z[rows][K], row-blocks RB of 256,
// K-tiles T of 64:  chunk(row,k) at
//   off = ((RB*KT + T)*2 + s)*16384 + g*4096 + (row&255)*16 + e*2
// B cols expert-interleaved: p = (o>>5)*256+((o>>3)&3)*64+(e>>1)*16+(o&7)*2+(e&1)
// =====================================================================

// ---- device-scope grid barrier (256 co-resident blocks; R4-proven) ----
__device__ __forceinline__ void gridbar(unsigned* bar, int idx, int nblk) {
  __syncthreads();
  if (threadIdx.x == 0) {
    __builtin_amdgcn_fence(__ATOMIC_RELEASE, "agent");
    __hip_atomic_fetch_add(&bar[idx * 16], 1u, __ATOMIC_RELAXED, __HIP_MEMORY_SCOPE_AGENT);
    while (__hip_atomic_load(&bar[idx * 16], __ATOMIC_RELAXED, __HIP_MEMORY_SCOPE_AGENT)
           < (unsigned)nblk)
      __builtin_amdgcn_s_sleep(8);
    __builtin_amdgcn_fence(__ATOMIC_ACQUIRE, "agent");
  }
  __syncthreads();
}

// ---- 512-thread weight tile stage ----
__device__ void wtile512(const float* __restrict__ w, __hip_bfloat16* __restrict__ out,
                         int Kin, int KT, int Oin, int oblk, int u, char* LDS)
{
  int kt = u % KT;
  int yy = u / KT;
  int e = yy / oblk;
  int o0 = (yy - e * oblk) << 6;
  int k0 = kt << 6;
  float* t = (float*)LDS;  // [64][65]
  int tid = threadIdx.x;
  int tx = tid & 63, ty = tid >> 6;  // 64 x 8
#pragma unroll
  for (int i = 0; i < 8; ++i) {
    int k = k0 + ty + i * 8;
    int o = o0 + tx;
    float v = (k < Kin && o < Oin) ? w[((size_t)e * Kin + k) * Oin + o] : 0.f;
    t[(ty + i * 8) * 65 + tx] = v;
  }
  __syncthreads();
  {
    int j = tid & 63, sg = tid >> 6;
    bf16x8 v;
#pragma unroll
    for (int e8 = 0; e8 < 8; ++e8) v[e8] = (__bf16)t[(sg * 8 + e8) * 65 + j];
    int o = o0 + j;
    int p = ((o >> 5) << 8) + (((o >> 3) & 3) << 6) + ((e >> 1) << 4) + ((o & 7) << 1) + (e & 1);
    size_t off = (((size_t)(p >> 8) * KT + kt) * 2 + (sg >> 2)) * 16384
               + (size_t)(sg & 3) * 4096 + (size_t)(p & 255) * 16;
    *(bf16x8*)((char*)out + off) = v;
  }
}

// ---- x0 staging unit: 512 chunks ----
__device__ void x0unit512(int u, const float* __restrict__ cond, const float* __restrict__ lat,
                          __hip_bfloat16* __restrict__ out)
{
  int c = u * 512 + threadIdx.x;
  int RB = c / 10240;
  int r1 = c - RB * 10240;
  int T = r1 >> 11, r2 = r1 & 2047;
  int n = RB * 256 + (r2 & 255);
  int k0 = T * 64 + (r2 >> 10) * 32 + ((r2 >> 8) & 3) * 8;
  bf16x8 v;
#pragma unroll
  for (int e = 0; e < 8; ++e) {
    int k = k0 + e;
    float f = (k < 219) ? cond[(size_t)n * 219 + k]
            : (k < 283) ? lat[(size_t)n * 64 + (k - 219)] : 0.f;
    v[e] = (__bf16)f;
  }
  *(bf16x8*)((char*)out + (size_t)c * 16) = v;
}

// ---- x1 latent unit (T=8 of KT=9): 512 chunks ----
__device__ void x1lat512(int u, const float* __restrict__ lat, __hip_bfloat16* __restrict__ out)
{
  int c = u * 512 + threadIdx.x;  // < 32768
  int RB = c >> 11, r2 = c & 2047;
  int n = RB * 256 + (r2 & 255);
  int k0 = (r2 >> 10) * 32 + ((r2 >> 8) & 3) * 8;
  bf16x8 v;
#pragma unroll
  for (int e = 0; e < 8; ++e) v[e] = (__bf16)lat[(size_t)n * 64 + k0 + e];
  size_t off = ((size_t)RB * 9 + 8) * 32768 + (size_t)r2 * 16;
  *(bf16x8*)((char*)out + off) = v;
}

// ---- gate layer: [64 x KTOT] x [KTOT x 128], chunked LDS weights (32 k-rows) ----
template <int KTOT>
__device__ void gate_layer(const float* __restrict__ Wg, const float* __restrict__ bias,
                           const float* gT, float* hT, float* wL, int tid)
{
  const int ct = tid & 31, rt = tid >> 5;   // 32 cols x 16 row-groups
  const int c0 = ct * 4, r0 = rt * 4;
  constexpr int NC = (KTOT + 31) / 32;
  constexpr int NF4 = KTOT * 32;            // total f32x4 in Wg
  f32x4 zf = {0.f, 0.f, 0.f, 0.f};
  f32x4 pre0, pre1;
  {
    int i0 = tid, i1 = tid + 512;
    pre0 = (i0 < NF4) ? ((const f32x4*)Wg)[i0] : zf;
    pre1 = (i1 < NF4) ? ((const f32x4*)Wg)[i1] : zf;
  }
  f32x4 a0 = {}, a1 = {}, a2 = {}, a3 = {};
  for (int c = 0; c < NC; ++c) {
    __syncthreads();
    ((f32x4*)wL)[tid] = pre0;
    ((f32x4*)wL)[tid + 512] = pre1;
    if (c + 1 < NC) {
      int i0 = (c + 1) * 1024 + tid, i1 = i0 + 512;
      pre0 = (i0 < NF4) ? ((const f32x4*)Wg)[i0] : zf;
      pre1 = (i1 < NF4) ? ((const f32x4*)Wg)[i1] : zf;
    }
    __syncthreads();
    const int kend = (c == NC - 1) ? (KTOT - 32 * (NC - 1)) : 32;
    for (int kk = 0; kk < kend; ++kk) {
      f32x4 g = *(const f32x4*)&gT[(c * 32 + kk) * 66 + r0];
      f32x4 w = *(const f32x4*)&wL[kk * 128 + c0];
      a0 += g * w[0]; a1 += g * w[1]; a2 += g * w[2]; a3 += g * w[3];
    }
  }
  f32x4 bb = *(const f32x4*)&bias[c0];
  a0 += bb[0]; a1 += bb[1]; a2 += bb[2]; a3 += bb[3];
#pragma unroll
  for (int j = 0; j < 4; ++j) {
    a0[j] = a0[j] > 0.f ? a0[j] : expm1f(a0[j]);
    a1[j] = a1[j] > 0.f ? a1[j] : expm1f(a1[j]);
    a2[j] = a2[j] > 0.f ? a2[j] : expm1f(a2[j]);
    a3[j] = a3[j] > 0.f ? a3[j] : expm1f(a3[j]);
  }
  *(f32x4*)&hT[(c0 + 0) * 66 + r0] = a0;
  *(f32x4*)&hT[(c0 + 1) * 66 + r0] = a1;
  *(f32x4*)&hT[(c0 + 2) * 66 + r0] = a2;
  *(f32x4*)&hT[(c0 + 3) * 66 + r0] = a3;
}

// ---- gate unit: 64 rows, 512 threads, exact fp32 ----
__device__ void gate512(int gb, const float* __restrict__ phs, const float* __restrict__ lat,
                        const float* __restrict__ gw1, const float* __restrict__ gb1_,
                        const float* __restrict__ gw2, const float* __restrict__ gb2_,
                        const float* __restrict__ gw3, const float* __restrict__ gb3_,
                        float* __restrict__ coeff, char* LDS)
{
  float* wL  = (float*)LDS;                        // 16384 B
  float* A   = (float*)(LDS + 16384);              // [128][66] f32 (g0T then h2T)
  float* h1T = (float*)(LDS + 16384 + 33792);      // [128][66]
  float* w3L = (float*)(LDS + 16384 + 67584);      // [128][8]
  const int tid = threadIdx.x;
  const int n0 = gb * 64;

  for (int i = tid; i < 104 * 64; i += 512) {
    int k = i >> 6, r = i & 63;
    A[k * 66 + r] = (k < 40) ? phs[(size_t)(n0 + r) * 40 + k]
                             : lat[(size_t)(n0 + r) * 64 + (k - 40)];
  }
  if (tid < 256) ((f32x4*)w3L)[tid] = ((const f32x4*)gw3)[tid];
  __syncthreads();
  gate_layer<104>(gw1, gb1_, A, h1T, wL, tid);
  __syncthreads();
  gate_layer<128>(gw2, gb2_, h1T, A, wL, tid);
  __syncthreads();
  {
    int row = tid >> 3, e = tid & 7;
    float acc = 0.f;
    for (int k = 0; k < 128; ++k) acc += A[k * 66 + row] * w3L[k * 8 + e];
    float lgt = acc + gb3_[e];
    float m = lgt;
    m = fmaxf(m, __shfl_xor(m, 1));
    m = fmaxf(m, __shfl_xor(m, 2));
    m = fmaxf(m, __shfl_xor(m, 4));
    float ex = expf(lgt - m);
    float s = ex;
    s += __shfl_xor(s, 1); s += __shfl_xor(s, 2); s += __shfl_xor(s, 4);
    coeff[(size_t)(n0 + row) * 8 + e] = ex / s;
  }
}

// ---- 8-phase K-tile (verified R3-R6) ----
#define MFMA_PHASE(NH)                                                                  \
  _Pragma("unroll") for (int fm = 0; fm < 8; ++fm) {                                    \
    acc[fm][2*(NH)]   = __builtin_amdgcn_mfma_f32_16x16x32_bf16(a[fm], b0, acc[fm][2*(NH)],   0, 0, 0); \
    acc[fm][2*(NH)+1] = __builtin_amdgcn_mfma_f32_16x16x32_bf16(a[fm], b1, acc[fm][2*(NH)+1], 0, 0, 0); \
  }

template <bool ST>
__device__ __forceinline__ void ktile(const char* cL, char* nL,
                                      const char* gA, const char* gB,
                                      int tid, int wid, int aoff, int boff,
                                      f32x4 (&acc)[8][4])
{
  bf16x8 a[8], b0, b1;
  const char* pa = cL;
  const char* pb = cL + 32768;
#pragma unroll
  for (int fm = 0; fm < 8; ++fm) a[fm] = *(const bf16x8*)(pa + aoff + fm * 256);
  b0 = *(const bf16x8*)(pb + boff + 0);
  b1 = *(const bf16x8*)(pb + boff + 256);
  if (ST) {
    gl_lds16(gA + tid * 16,        nL + (wid << 10));
    gl_lds16(gA + 8192 + tid * 16, nL + 8192 + (wid << 10));
  }
  __builtin_amdgcn_s_barrier();
  __builtin_amdgcn_s_setprio(1);
  MFMA_PHASE(0);
  __builtin_amdgcn_s_setprio(0);
  __builtin_amdgcn_s_barrier();
  b0 = *(const bf16x8*)(pb + boff + 512);
  b1 = *(const bf16x8*)(pb + boff + 768);
  if (ST) {
    gl_lds16(gB + tid * 16,        nL + 32768 + (wid << 10));
    gl_lds16(gB + 8192 + tid * 16, nL + 32768 + 8192 + (wid << 10));
  }
  __builtin_amdgcn_s_barrier();
  __builtin_amdgcn_s_setprio(1);
  MFMA_PHASE(1);
  __builtin_amdgcn_s_setprio(0);
  if (ST) asm volatile("s_waitcnt vmcnt(4)" ::: "memory");
  else    asm volatile("s_waitcnt vmcnt(0)" ::: "memory");
  __builtin_amdgcn_s_barrier();
  pa = cL + 16384; pb = cL + 32768 + 16384;
#pragma unroll
  for (int fm = 0; fm < 8; ++fm) a[fm] = *(const bf16x8*)(pa + aoff + fm * 256);
  b0 = *(const bf16x8*)(pb + boff + 0);
  b1 = *(const bf16x8*)(pb + boff + 256);
  if (ST) {
    gl_lds16(gA + 16384 + tid * 16,        nL + 16384 + (wid << 10));
    gl_lds16(gA + 16384 + 8192 + tid * 16, nL + 16384 + 8192 + (wid << 10));
  }
  __builtin_amdgcn_s_barrier();
  __builtin_amdgcn_s_setprio(1);
  MFMA_PHASE(0);
  __builtin_amdgcn_s_setprio(0);
  __builtin_amdgcn_s_barrier();
  b0 = *(const bf16x8*)(pb + boff + 512);
  b1 = *(const bf16x8*)(pb + boff + 768);
  if (ST) {
    gl_lds16(gB + 16384 + tid * 16,        nL + 32768 + 16384 + (wid << 10));
    gl_lds16(gB + 16384 + 8192 + tid * 16, nL + 32768 + 16384 + 8192 + (wid << 10));
  }
  __builtin_amdgcn_s_barrier();
  __builtin_amdgcn_s_setprio(1);
  MFMA_PHASE(1);
  __builtin_amdgcn_s_setprio(0);
  if (ST) asm volatile("s_waitcnt vmcnt(4)" ::: "memory");
  __builtin_amdgcn_s_barrier();
}

// ---- GEMM phase: 256x256 tile + fused blend (MODE 0: staged bf16, 1: fp32) ----
template <int KT, int KTD, int MODE>
__device__ void gemm_phase(const __hip_bfloat16* __restrict__ Ap,
                           const __hip_bfloat16* __restrict__ Bp,
                           const float* __restrict__ coeff, const float* __restrict__ bias,
                           __hip_bfloat16* __restrict__ dstS, float* __restrict__ dstF,
                           int bx, int by, char* lds)
{
  const int tid = threadIdx.x;
  const int lane = tid & 63;
  const int wid = tid >> 6;
  const int wr = wid >> 2, wc = wid & 3;
  const int l15 = lane & 15, lg = lane >> 4;
  const int aoff = lg * 4096 + wr * 2048 + l15 * 16;
  const int boff = lg * 4096 + wc * 1024 + l15 * 16;

  const char* aG = (const char*)Ap + (size_t)bx * KT * 32768;
  const char* bG = (const char*)Bp + (size_t)by * KT * 32768;

  f32x4 acc[8][4] = {};

  {
    char* L = lds;
    gl_lds16(aG + tid * 16,                 L + (wid << 10));
    gl_lds16(aG + 8192 + tid * 16,          L + 8192 + (wid << 10));
    gl_lds16(bG + tid * 16,                 L + 32768 + (wid << 10));
    gl_lds16(bG + 8192 + tid * 16,          L + 32768 + 8192 + (wid << 10));
    gl_lds16(aG + 16384 + tid * 16,         L + 16384 + (wid << 10));
    gl_lds16(aG + 16384 + 8192 + tid * 16,  L + 16384 + 8192 + (wid << 10));
    gl_lds16(bG + 16384 + tid * 16,         L + 32768 + 16384 + (wid << 10));
    gl_lds16(bG + 16384 + 8192 + tid * 16,  L + 32768 + 16384 + 8192 + (wid << 10));
    asm volatile("s_waitcnt vmcnt(4)" ::: "memory");
    __builtin_amdgcn_s_barrier();
  }

  for (int t = 0; t < KT; ++t) {
    const char* cL = lds + ((t & 1) << 16);
    char* nL = lds + (((t + 1) & 1) << 16);
    const char* gA = aG + (size_t)(t + 1) * 32768;
    const char* gB = bG + (size_t)(t + 1) * 32768;
    if (t + 1 < KT) ktile<true>(cL, nL, gA, gB, tid, wid, aoff, boff, acc);
    else            ktile<false>(cL, nL, gA, gB, tid, wid, aoff, boff, acc);
  }

  // fused expert-blend epilogue (coeff transposed [8][258]: conflict-free)
  float* cl2 = (float*)lds;
  {
#pragma unroll
    for (int i = 0; i < 4; ++i) {
      int idx = i * 512 + tid;
      int e = idx & 7, n = idx >> 3;
      cl2[e * 258 + n] = coeff[((size_t)bx * 256 + n) * 8 + e];
    }
  }
  __syncthreads();
  const int e0 = lane & 1;
  const int o_loc = (wc << 3) + (l15 >> 1);

  if (MODE == 0) {
    float* tb = (float*)(lds + 8448);  // [256][33] f32
    float bb[4];
#pragma unroll
    for (int fn = 0; fn < 4; ++fn) bb[fn] = bias[(fn * 2 + e0) * 512 + by * 32 + o_loc];
#pragma unroll
    for (int fm = 0; fm < 8; ++fm) {
#pragma unroll
      for (int r = 0; r < 4; ++r) {
        int n_loc = wr * 128 + fm * 16 + (lg << 2) + r;
        float s = 0.f;
#pragma unroll
        for (int fn = 0; fn < 4; ++fn)
          s += cl2[(fn * 2 + e0) * 258 + n_loc] * (acc[fm][fn][r] + bb[fn]);
        s += __shfl_xor(s, 1);
        s = s > 0.f ? s : expm1f(s);
        if ((lane & 1) == (fm & 1)) tb[n_loc * 33 + o_loc] = s;
      }
    }
    __syncthreads();
#pragma unroll
    for (int it = 0; it < 2; ++it) {
      int ch = it * 512 + tid;
      int n_loc = ch & 255, c = ch >> 8;
      const float* p = &tb[n_loc * 33 + c * 8];
      bf16x8 v;
#pragma unroll
      for (int j = 0; j < 8; ++j) v[j] = (__bf16)p[j];
      size_t off = (((size_t)bx * KTD + (by >> 1)) * 2 + (by & 1)) * 16384
                 + (size_t)c * 4096 + (size_t)n_loc * 16;
      *(bf16x8*)((char*)dstS + off) = v;
    }
  } else {
    const int o_g = by * 32 + o_loc;
    if (o_g < 171) {
      float bb[4];
#pragma unroll
      for (int fn = 0; fn < 4; ++fn) bb[fn] = bias[(fn * 2 + e0) * 171 + o_g];
#pragma unroll
      for (int fm = 0; fm < 8; ++fm) {
#pragma unroll
        for (int r = 0; r < 4; ++r) {
          int n_loc = wr * 128 + fm * 16 + (lg << 2) + r;
          float s = 0.f;
#pragma unroll
          for (int fn = 0; fn < 4; ++fn)
            s += cl2[(fn * 2 + e0) * 258 + n_loc] * (acc[fm][fn][r] + bb[fn]);
          s += __shfl_xor(s, 1);
          if ((lane & 1) == (fm & 1))
            dstF[(size_t)(bx * 256 + n_loc) * 171 + o_g] = s;
        }
      }
    }
  }
  __syncthreads();
}

// ---- mega v2: grid 256 x 512, balanced prep + 3 gemm phases ----
__global__ __launch_bounds__(512, 2) void mega(
    const float* __restrict__ latent, const float* __restrict__ condition,
    const float* __restrict__ phase,
    const float* __restrict__ gw1, const float* __restrict__ gb1,
    const float* __restrict__ gw2, const float* __restrict__ gb2,
    const float* __restrict__ gw3, const float* __restrict__ gb3,
    const float* __restrict__ w0, const float* __restrict__ b0,
    const float* __restrict__ w1, const float* __restrict__ b1,
    const float* __restrict__ w2, const float* __restrict__ b2,
    __hip_bfloat16* x0s, __hip_bfloat16* x1s, __hip_bfloat16* x2s,
    __hip_bfloat16* w0s, __hip_bfloat16* w1s, __hip_bfloat16* w2s,
    float* out, float* coeff, unsigned* bar)
{
  __shared__ __align__(16) char LDS[131072];
  const int bid = blockIdx.x;

  // ---- P0: prep, 1536 units over 6 rounds ----
  // cheap(j): j<320 -> x0unit512(j); else x1lat512(j-320)     [384 units]
  // heavy(i): i<320 w0-tile; <896 w1-tile; <1088 w2-tile; else cheap(320+i-1088)
  if (bid < 64) {
    gate512(bid, phase, latent, gw1, gb1, gw2, gb2, gw3, gb3, coeff, LDS);
    __syncthreads();
#pragma unroll 1
    for (int r = 1; r < 6; ++r) {
      int j = (r - 1) * 64 + bid;          // 0..319 -> all x0 units
      x0unit512(j, condition, latent, x0s);
      __syncthreads();
    }
  } else {
    int hb = bid - 64;
#pragma unroll 1
    for (int r = 0; r < 6; ++r) {
      int i = hb * 6 + r;                  // 0..1151
      if (i < 320)        wtile512(w0, w0s, 283, 5, 512, 8, i, LDS);
      else if (i < 896)   wtile512(w1, w1s, 576, 9, 512, 8, i - 320, LDS);
      else if (i < 1088)  wtile512(w2, w2s, 512, 8, 171, 3, i - 896, LDS);
      else                x1lat512(i - 1088, latent, x1s);   // 64 units
      __syncthreads();
    }
  }
  gridbar(bar, 0, 256);

  // ---- P1: layer 0 (XCD-swizzled: 32 consecutive sb per XCD) ----
  {
    int sb = ((bid & 7) << 5) | (bid >> 3);
    gemm_phase<5, 9, 0>(x0s, w0s, coeff, b0, x1s, nullptr, sb & 15, sb >> 4, LDS);
  }
  gridbar(bar, 1, 256);

  // ---- P2: layer 1 ----
  {
    int sb = ((bid & 7) << 5) | (bid >> 3);
    gemm_phase<9, 8, 0>(x1s, w1s, coeff, b1, x2s, nullptr, sb & 15, sb >> 4, LDS);
  }
  gridbar(bar, 2, 256);

  // ---- P3: layer 2 (96 blocks) ----
  if (bid < 96) {
    int s2 = (bid & 7) * 12 + (bid >> 3);
    gemm_phase<8, 0, 1>(x2s, w2s, coeff, b2, nullptr, out, s2 & 15, s2 >> 4, LDS);
  }
}

// ---------------- launch ----------------
extern "C" void kernel_launch(void* const* d_in, const int* in_sizes, int n_in,
                              void* d_out, int out_size, void* d_ws, size_t ws_size,
                              hipStream_t stream)
{
  const float* latent    = (const float*)d_in[0];
  const float* condition = (const float*)d_in[1];
  const float* phase     = (const float*)d_in[2];
  const float* gw1 = (const float*)d_in[3];
  const float* gb1 = (const float*)d_in[4];
  const float* gw2 = (const float*)d_in[5];
  const float* gb2 = (const float*)d_in[6];
  const float* gw3 = (const float*)d_in[7];
  const float* gb3 = (const float*)d_in[8];
  const float* w0  = (const float*)d_in[9];
  const float* b0  = (const float*)d_in[10];
  const float* w1  = (const float*)d_in[11];
  const float* b1  = (const float*)d_in[12];
  const float* w2  = (const float*)d_in[13];
  const float* b2  = (const float*)d_in[14];

  float* out   = (float*)d_out;
  float* coeff = out + (size_t)NR * 171;

  char* ws = (char*)d_ws;
  __hip_bfloat16* x0s = (__hip_bfloat16*)ws; ws += (size_t)16 * 5 * 32768;
  __hip_bfloat16* x1s = (__hip_bfloat16*)ws; ws += (size_t)16 * 9 * 32768;
  __hip_bfloat16* x2s = (__hip_bfloat16*)ws; ws += (size_t)16 * 8 * 32768;
  __hip_bfloat16* w0s = (__hip_bfloat16*)ws; ws += (size_t)16 * 5 * 32768;
  __hip_bfloat16* w1s = (__hip_bfloat16*)ws; ws += (size_t)16 * 9 * 32768;
  __hip_bfloat16* w2s = (__hip_bfloat16*)ws; ws += (size_t)6 * 8 * 32768;
  unsigned* bar = (unsigned*)ws;

  hipMemsetAsync(bar, 0, 256, stream);
  mega<<<256, 512, 0, stream>>>(latent, condition, phase,
                                gw1, gb1, gw2, gb2, gw3, gb3,
                                w0, b0, w1, b1, w2, b2,
                                x0s, x1s, x2s, w0s, w1s, w2s,
                                out, coeff, bar);
}

// Round 8
// 98.234 us; speedup vs baseline: 5.7666x; 5.7666x over previous
//
#include <hip/hip_runtime.h>
#include <hip/hip_bf16.h>

#define NR 4096

typedef float f32x4 __attribute__((ext_vector_type(4)));
typedef __bf16 bf16x8 __attribute__((ext_vector_type(8)));

typedef __attribute__((address_space(1))) unsigned int u32_g;
typedef __attribute__((address_space(3))) unsigned int u32_l;

__device__ __forceinline__ void gl_lds16(const void* g, void* l) {
  __builtin_amdgcn_global_load_lds((const u32_g*)g, (u32_l*)l, 16, 0, 0);
}

// =====================================================================
// Staged operand layout (bf16): logical Z[rows][K], row-blocks RB of 256,
// K-tiles T of 64:  chunk(row,k) at
//   off = ((RB*KT + T)*2 + s)*16384 + g*4096 + (row&255)*16 + e*2
// B cols expert-interleaved: p = (o>>5)*256+((o>>3)&3)*64+(e>>1)*16+(o&7)*2+(e&1)
//   => in-tile: e = fn*2+(l15&1), o = by*32 + wc*8 + (l15>>1)
// =====================================================================

// ---- 256-thread weight tile stage ----
__device__ void wtile256(const float* __restrict__ w, __hip_bfloat16* __restrict__ out,
                         int Kin, int KT, int Oin, int oblk, int u, char* LDS)
{
  int kt = u % KT;
  int yy = u / KT;
  int e = yy / oblk;
  int o0 = (yy - e * oblk) << 6;
  int k0 = kt << 6;
  float* t = (float*)LDS;  // [64][65]
  int tid = threadIdx.x;
  int tx = tid & 63, ty = tid >> 6;  // 64 x 4
#pragma unroll
  for (int i = 0; i < 16; ++i) {
    int k = k0 + ty + i * 4;
    int o = o0 + tx;
    float v = (k < Kin && o < Oin) ? w[((size_t)e * Kin + k) * Oin + o] : 0.f;
    t[(ty + i * 4) * 65 + tx] = v;
  }
  __syncthreads();
#pragma unroll
  for (int it = 0; it < 2; ++it) {
    int c = it * 256 + tid;
    int j = c & 63, sg = c >> 6;
    bf16x8 v;
#pragma unroll
    for (int e8 = 0; e8 < 8; ++e8) v[e8] = (__bf16)t[(sg * 8 + e8) * 65 + j];
    int o = o0 + j;
    int p = ((o >> 5) << 8) + (((o >> 3) & 3) << 6) + ((e >> 1) << 4) + ((o & 7) << 1) + (e & 1);
    size_t off = (((size_t)(p >> 8) * KT + kt) * 2 + (sg >> 2)) * 16384
               + (size_t)(sg & 3) * 4096 + (size_t)(p & 255) * 16;
    *(bf16x8*)((char*)out + off) = v;
  }
}

// ---- x0 staging unit: 256 chunks ----
__device__ void x0unit(int u, const float* __restrict__ cond, const float* __restrict__ lat,
                       __hip_bfloat16* __restrict__ out)
{
  int c = u * 256 + threadIdx.x;
  int RB = c / 10240;
  int r1 = c - RB * 10240;
  int T = r1 >> 11, r2 = r1 & 2047;
  int n = RB * 256 + (r2 & 255);
  int k0 = T * 64 + (r2 >> 10) * 32 + ((r2 >> 8) & 3) * 8;
  bf16x8 v;
#pragma unroll
  for (int e = 0; e < 8; ++e) {
    int k = k0 + e;
    float f = (k < 219) ? cond[(size_t)n * 219 + k]
            : (k < 283) ? lat[(size_t)n * 64 + (k - 219)] : 0.f;
    v[e] = (__bf16)f;
  }
  *(bf16x8*)((char*)out + (size_t)c * 16) = v;
}

// ---- x1 latent unit (T=8 of KT=9): 256 chunks ----
__device__ void x1lat(int u, const float* __restrict__ lat, __hip_bfloat16* __restrict__ out)
{
  int c = u * 256 + threadIdx.x;  // 0..32767
  int RB = c >> 11, r2 = c & 2047;
  int n = RB * 256 + (r2 & 255);
  int k0 = (r2 >> 10) * 32 + ((r2 >> 8) & 3) * 8;
  bf16x8 v;
#pragma unroll
  for (int e = 0; e < 8; ++e) v[e] = (__bf16)lat[(size_t)n * 64 + k0 + e];
  size_t off = ((size_t)RB * 9 + 8) * 32768 + (size_t)r2 * 16;
  *(bf16x8*)((char*)out + off) = v;
}

// ---- prepS: ALL staging, one wide kernel, every block independent ----
__global__ __launch_bounds__(256) void prepS(
    const float* __restrict__ latent, const float* __restrict__ condition,
    const float* __restrict__ w0, const float* __restrict__ w1, const float* __restrict__ w2,
    __hip_bfloat16* x0s, __hip_bfloat16* x1s,
    __hip_bfloat16* w0s, __hip_bfloat16* w1s, __hip_bfloat16* w2s)
{
  __shared__ __align__(16) char LDS[64 * 65 * 4];
  int b = blockIdx.x;
  if (b < 320)       wtile256(w0, w0s, 283, 5, 512, 8, b, LDS);
  else if (b < 896)  wtile256(w1, w1s, 576, 9, 512, 8, b - 320, LDS);
  else if (b < 1088) wtile256(w2, w2s, 512, 8, 171, 3, b - 896, LDS);
  else if (b < 1152) {
    int u0 = b - 1088;
    x1lat(u0, latent, x1s);
    x1lat(u0 + 64, latent, x1s);
  } else {
    x0unit(b - 1152, condition, latent, x0s);  // 640 units
  }
}

// ---- gate kernel: LDS-cached weights, 4x4 register-blocked, exact fp32 ----
// 128 blocks x 256 threads; block handles 32 rows.
__global__ __launch_bounds__(256) void gate_k(
    const float* __restrict__ phs, const float* __restrict__ lat,
    const float* __restrict__ gw1, const float* __restrict__ gb1,
    const float* __restrict__ gw2, const float* __restrict__ gb2,
    const float* __restrict__ gw3, const float* __restrict__ gb3,
    float* __restrict__ coeff)
{
  __shared__ __align__(16) float wL[128 * 128];   // 64KB, reused w1 -> w2
  __shared__ __align__(16) float g0T[104 * 36];   // [k][row]
  __shared__ __align__(16) float h1T[128 * 36];
  __shared__ __align__(16) float h2T[128 * 36];
  __shared__ __align__(16) float w3L[128 * 8];
  const int tid = threadIdx.x;
  const int n0 = blockIdx.x * 32;

  // stage g0T (fp32 inputs, transposed [k][row])
  for (int i = tid; i < 104 * 32; i += 256) {
    int k = i >> 5, r = i & 31;
    g0T[k * 36 + r] = (k < 40) ? phs[(size_t)(n0 + r) * 40 + k]
                               : lat[(size_t)(n0 + r) * 64 + (k - 40)];
  }
  // stage w1 (contiguous 104x128 f32) + w3 — independent pipelined float4 loads
  for (int i = tid; i < 104 * 32; i += 256) ((float4*)wL)[i] = ((const float4*)gw1)[i];
  ((float4*)w3L)[tid] = ((const float4*)gw3)[tid];
  __syncthreads();

  const int ct = tid & 31, rt = tid >> 5;
  const int c0 = ct << 2, r0 = rt << 2;

  // ---- layer 1: [32 x 104] x [104 x 128] ----
  {
    f32x4 a0 = {}, a1 = {}, a2 = {}, a3 = {};
    for (int k = 0; k < 104; ++k) {
      f32x4 g = *(const f32x4*)&g0T[k * 36 + r0];
      f32x4 w = *(const f32x4*)&wL[k * 128 + c0];
      a0 += g * w.x; a1 += g * w.y; a2 += g * w.z; a3 += g * w.w;
    }
    f32x4 bb = *(const f32x4*)&gb1[c0];
    a0 += bb.x; a1 += bb.y; a2 += bb.z; a3 += bb.w;
#pragma unroll
    for (int j = 0; j < 4; ++j) {
      a0[j] = a0[j] > 0.f ? a0[j] : expm1f(a0[j]);
      a1[j] = a1[j] > 0.f ? a1[j] : expm1f(a1[j]);
      a2[j] = a2[j] > 0.f ? a2[j] : expm1f(a2[j]);
      a3[j] = a3[j] > 0.f ? a3[j] : expm1f(a3[j]);
    }
    *(f32x4*)&h1T[(c0 + 0) * 36 + r0] = a0;
    *(f32x4*)&h1T[(c0 + 1) * 36 + r0] = a1;
    *(f32x4*)&h1T[(c0 + 2) * 36 + r0] = a2;
    *(f32x4*)&h1T[(c0 + 3) * 36 + r0] = a3;
  }
  __syncthreads();
  // stage w2 (128x128 f32) over wL
  for (int i = tid; i < 128 * 32; i += 256) ((float4*)wL)[i] = ((const float4*)gw2)[i];
  __syncthreads();

  // ---- layer 2: [32 x 128] x [128 x 128] ----
  {
    f32x4 a0 = {}, a1 = {}, a2 = {}, a3 = {};
    for (int k = 0; k < 128; ++k) {
      f32x4 g = *(const f32x4*)&h1T[k * 36 + r0];
      f32x4 w = *(const f32x4*)&wL[k * 128 + c0];
      a0 += g * w.x; a1 += g * w.y; a2 += g * w.z; a3 += g * w.w;
    }
    f32x4 bb = *(const f32x4*)&gb2[c0];
    a0 += bb.x; a1 += bb.y; a2 += bb.z; a3 += bb.w;
#pragma unroll
    for (int j = 0; j < 4; ++j) {
      a0[j] = a0[j] > 0.f ? a0[j] : expm1f(a0[j]);
      a1[j] = a1[j] > 0.f ? a1[j] : expm1f(a1[j]);
      a2[j] = a2[j] > 0.f ? a2[j] : expm1f(a2[j]);
      a3[j] = a3[j] > 0.f ? a3[j] : expm1f(a3[j]);
    }
    *(f32x4*)&h2T[(c0 + 0) * 36 + r0] = a0;
    *(f32x4*)&h2T[(c0 + 1) * 36 + r0] = a1;
    *(f32x4*)&h2T[(c0 + 2) * 36 + r0] = a2;
    *(f32x4*)&h2T[(c0 + 3) * 36 + r0] = a3;
  }
  __syncthreads();

  // ---- layer 3 + softmax: thread (row = tid>>3, e = tid&7) ----
  {
    int row = tid >> 3, e = tid & 7;
    float acc = 0.f;
    for (int k = 0; k < 128; ++k) acc += h2T[k * 36 + row] * w3L[k * 8 + e];
    float lgt = acc + gb3[e];
    float m = lgt;
    m = fmaxf(m, __shfl_xor(m, 1));
    m = fmaxf(m, __shfl_xor(m, 2));
    m = fmaxf(m, __shfl_xor(m, 4));
    float ex = expf(lgt - m);
    float s = ex;
    s += __shfl_xor(s, 1);
    s += __shfl_xor(s, 2);
    s += __shfl_xor(s, 4);
    coeff[(size_t)(n0 + row) * 8 + e] = ex / s;
  }
}

// ---- 8-phase K-tile (verified R3-R6) ----
#define MFMA_PHASE(NH)                                                                  \
  _Pragma("unroll") for (int fm = 0; fm < 8; ++fm) {                                    \
    acc[fm][2*(NH)]   = __builtin_amdgcn_mfma_f32_16x16x32_bf16(a[fm], b0, acc[fm][2*(NH)],   0, 0, 0); \
    acc[fm][2*(NH)+1] = __builtin_amdgcn_mfma_f32_16x16x32_bf16(a[fm], b1, acc[fm][2*(NH)+1], 0, 0, 0); \
  }

template <bool ST>
__device__ __forceinline__ void ktile(const char* cL, char* nL,
                                      const char* gA, const char* gB,
                                      int tid, int wid, int aoff, int boff,
                                      f32x4 (&acc)[8][4])
{
  bf16x8 a[8], b0, b1;
  const char* pa = cL;
  const char* pb = cL + 32768;
#pragma unroll
  for (int fm = 0; fm < 8; ++fm) a[fm] = *(const bf16x8*)(pa + aoff + fm * 256);
  b0 = *(const bf16x8*)(pb + boff + 0);
  b1 = *(const bf16x8*)(pb + boff + 256);
  if (ST) {
    gl_lds16(gA + tid * 16,        nL + (wid << 10));
    gl_lds16(gA + 8192 + tid * 16, nL + 8192 + (wid << 10));
  }
  __builtin_amdgcn_s_barrier();
  __builtin_amdgcn_s_setprio(1);
  MFMA_PHASE(0);
  __builtin_amdgcn_s_setprio(0);
  __builtin_amdgcn_s_barrier();
  b0 = *(const bf16x8*)(pb + boff + 512);
  b1 = *(const bf16x8*)(pb + boff + 768);
  if (ST) {
    gl_lds16(gB + tid * 16,        nL + 32768 + (wid << 10));
    gl_lds16(gB + 8192 + tid * 16, nL + 32768 + 8192 + (wid << 10));
  }
  __builtin_amdgcn_s_barrier();
  __builtin_amdgcn_s_setprio(1);
  MFMA_PHASE(1);
  __builtin_amdgcn_s_setprio(0);
  if (ST) asm volatile("s_waitcnt vmcnt(4)" ::: "memory");
  else    asm volatile("s_waitcnt vmcnt(0)" ::: "memory");
  __builtin_amdgcn_s_barrier();
  pa = cL + 16384; pb = cL + 32768 + 16384;
#pragma unroll
  for (int fm = 0; fm < 8; ++fm) a[fm] = *(const bf16x8*)(pa + aoff + fm * 256);
  b0 = *(const bf16x8*)(pb + boff + 0);
  b1 = *(const bf16x8*)(pb + boff + 256);
  if (ST) {
    gl_lds16(gA + 16384 + tid * 16,        nL + 16384 + (wid << 10));
    gl_lds16(gA + 16384 + 8192 + tid * 16, nL + 16384 + 8192 + (wid << 10));
  }
  __builtin_amdgcn_s_barrier();
  __builtin_amdgcn_s_setprio(1);
  MFMA_PHASE(0);
  __builtin_amdgcn_s_setprio(0);
  __builtin_amdgcn_s_barrier();
  b0 = *(const bf16x8*)(pb + boff + 512);
  b1 = *(const bf16x8*)(pb + boff + 768);
  if (ST) {
    gl_lds16(gB + 16384 + tid * 16,        nL + 32768 + 16384 + (wid << 10));
    gl_lds16(gB + 16384 + 8192 + tid * 16, nL + 32768 + 16384 + 8192 + (wid << 10));
  }
  __builtin_amdgcn_s_barrier();
  __builtin_amdgcn_s_setprio(1);
  MFMA_PHASE(1);
  __builtin_amdgcn_s_setprio(0);
  if (ST) asm volatile("s_waitcnt vmcnt(4)" ::: "memory");
  __builtin_amdgcn_s_barrier();
}

// ---- pure GEMM kernel (256x256 tile, fused expert-blend epilogue) ----
// MODE 0 -> staged bf16 next-layer activations; MODE 1 -> fp32 final out.
// BYG: by-values per XCD-half — rectangular XCD swizzle so each XCD works a
// 4(bx) x BYG(by) rectangle: per-XCD L2 footprint = 4 A-panels + BYG B-panels.
template <int KT, int KTD, int MODE, int BYG>
__global__ __launch_bounds__(512, 2) void gemm_k(
    const __hip_bfloat16* __restrict__ Ap, const __hip_bfloat16* __restrict__ Bp,
    const float* __restrict__ coeff, const float* __restrict__ bias,
    __hip_bfloat16* __restrict__ dstS, float* __restrict__ dstF)
{
  __shared__ __align__(16) char lds[131072];
  const int bid = blockIdx.x;
  const int xcd = bid & 7, l = bid >> 3;
  const int bx = ((xcd & 3) << 2) + (l & 3);
  const int by = (xcd >> 2) * BYG + (l >> 2);
  const int tid = threadIdx.x;
  const int lane = tid & 63;
  const int wid = tid >> 6;
  const int wr = wid >> 2, wc = wid & 3;
  const int l15 = lane & 15, lg = lane >> 4;
  const int aoff = lg * 4096 + wr * 2048 + l15 * 16;
  const int boff = lg * 4096 + wc * 1024 + l15 * 16;

  const char* aG = (const char*)Ap + (size_t)bx * KT * 32768;
  const char* bG = (const char*)Bp + (size_t)by * KT * 32768;

  f32x4 acc[8][4] = {};

  {
    char* L = lds;
    gl_lds16(aG + tid * 16,                 L + (wid << 10));
    gl_lds16(aG + 8192 + tid * 16,          L + 8192 + (wid << 10));
    gl_lds16(bG + tid * 16,                 L + 32768 + (wid << 10));
    gl_lds16(bG + 8192 + tid * 16,          L + 32768 + 8192 + (wid << 10));
    gl_lds16(aG + 16384 + tid * 16,         L + 16384 + (wid << 10));
    gl_lds16(aG + 16384 + 8192 + tid * 16,  L + 16384 + 8192 + (wid << 10));
    gl_lds16(bG + 16384 + tid * 16,         L + 32768 + 16384 + (wid << 10));
    gl_lds16(bG + 16384 + 8192 + tid * 16,  L + 32768 + 16384 + 8192 + (wid << 10));
    asm volatile("s_waitcnt vmcnt(4)" ::: "memory");
    __builtin_amdgcn_s_barrier();
  }

  for (int t = 0; t < KT; ++t) {
    const char* cL = lds + ((t & 1) << 16);
    char* nL = lds + (((t + 1) & 1) << 16);
    const char* gA = aG + (size_t)(t + 1) * 32768;
    const char* gB = bG + (size_t)(t + 1) * 32768;
    if (t + 1 < KT) ktile<true>(cL, nL, gA, gB, tid, wid, aoff, boff, acc);
    else            ktile<false>(cL, nL, gA, gB, tid, wid, aoff, boff, acc);
  }

  // ---- fused expert-blend epilogue (coeff transposed [8][258]: conflict-free) ----
  float* cl2 = (float*)lds;
  {
#pragma unroll
    for (int i = 0; i < 4; ++i) {
      int idx = i * 512 + tid;
      int e = idx & 7, n = idx >> 3;
      cl2[e * 258 + n] = coeff[((size_t)bx * 256 + n) * 8 + e];
    }
  }
  __syncthreads();
  const int e0 = lane & 1;
  const int o_loc = (wc << 3) + (l15 >> 1);

  if (MODE == 0) {
    float* tb = (float*)(lds + 8448);  // [256][33] f32
    float bb[4];
#pragma unroll
    for (int fn = 0; fn < 4; ++fn) bb[fn] = bias[(fn * 2 + e0) * 512 + by * 32 + o_loc];
#pragma unroll
    for (int fm = 0; fm < 8; ++fm) {
#pragma unroll
      for (int r = 0; r < 4; ++r) {
        int n_loc = wr * 128 + fm * 16 + (lg << 2) + r;
        float s = 0.f;
#pragma unroll
        for (int fn = 0; fn < 4; ++fn)
          s += cl2[(fn * 2 + e0) * 258 + n_loc] * (acc[fm][fn][r] + bb[fn]);
        s += __shfl_xor(s, 1);
        s = s > 0.f ? s : expm1f(s);
        if ((lane & 1) == (fm & 1)) tb[n_loc * 33 + o_loc] = s;
      }
    }
    __syncthreads();
#pragma unroll
    for (int it = 0; it < 2; ++it) {
      int ch = it * 512 + tid;
      int n_loc = ch & 255, c = ch >> 8;
      const float* p = &tb[n_loc * 33 + c * 8];
      bf16x8 v;
#pragma unroll
      for (int j = 0; j < 8; ++j) v[j] = (__bf16)p[j];
      size_t off = (((size_t)bx * KTD + (by >> 1)) * 2 + (by & 1)) * 16384
                 + (size_t)c * 4096 + (size_t)n_loc * 16;
      *(bf16x8*)((char*)dstS + off) = v;
    }
  } else {
    const int o_g = by * 32 + o_loc;
    if (o_g < 171) {
      float bb[4];
#pragma unroll
      for (int fn = 0; fn < 4; ++fn) bb[fn] = bias[(fn * 2 + e0) * 171 + o_g];
#pragma unroll
      for (int fm = 0; fm < 8; ++fm) {
#pragma unroll
        for (int r = 0; r < 4; ++r) {
          int n_loc = wr * 128 + fm * 16 + (lg << 2) + r;
          float s = 0.f;
#pragma unroll
          for (int fn = 0; fn < 4; ++fn)
            s += cl2[(fn * 2 + e0) * 258 + n_loc] * (acc[fm][fn][r] + bb[fn]);
          s += __shfl_xor(s, 1);
          if ((lane & 1) == (fm & 1))
            dstF[(size_t)(bx * 256 + n_loc) * 171 + o_g] = s;
        }
      }
    }
  }
}

// ---------------- launch ----------------
extern "C" void kernel_launch(void* const* d_in, const int* in_sizes, int n_in,
                              void* d_out, int out_size, void* d_ws, size_t ws_size,
                              hipStream_t stream)
{
  const float* latent    = (const float*)d_in[0];
  const float* condition = (const float*)d_in[1];
  const float* phase     = (const float*)d_in[2];
  const float* gw1 = (const float*)d_in[3];
  const float* gb1 = (const float*)d_in[4];
  const float* gw2 = (const float*)d_in[5];
  const float* gb2 = (const float*)d_in[6];
  const float* gw3 = (const float*)d_in[7];
  const float* gb3 = (const float*)d_in[8];
  const float* w0  = (const float*)d_in[9];
  const float* b0  = (const float*)d_in[10];
  const float* w1  = (const float*)d_in[11];
  const float* b1  = (const float*)d_in[12];
  const float* w2  = (const float*)d_in[13];
  const float* b2  = (const float*)d_in[14];

  float* out   = (float*)d_out;
  float* coeff = out + (size_t)NR * 171;

  char* ws = (char*)d_ws;
  __hip_bfloat16* x0s = (__hip_bfloat16*)ws; ws += (size_t)16 * 5 * 32768;
  __hip_bfloat16* x1s = (__hip_bfloat16*)ws; ws += (size_t)16 * 9 * 32768;
  __hip_bfloat16* x2s = (__hip_bfloat16*)ws; ws += (size_t)16 * 8 * 32768;
  __hip_bfloat16* w0s = (__hip_bfloat16*)ws; ws += (size_t)16 * 5 * 32768;
  __hip_bfloat16* w1s = (__hip_bfloat16*)ws; ws += (size_t)16 * 9 * 32768;
  __hip_bfloat16* w2s = (__hip_bfloat16*)ws; ws += (size_t)6 * 8 * 32768;

  // K1: gate (exact fp32, LDS-cached weights)
  gate_k<<<128, 256, 0, stream>>>(phase, latent, gw1, gb1, gw2, gb2, gw3, gb3, coeff);

  // K2: all staging in parallel — w0(320) w1(576) w2(192) x1lat(64) x0(640)
  prepS<<<1792, 256, 0, stream>>>(latent, condition, w0, w1, w2,
                                  x0s, x1s, w0s, w1s, w2s);

  // K3-K5: pure fused GEMMs (rectangular XCD swizzle: 4bx x BYG-by per XCD)
  gemm_k<5, 9, 0, 8><<<256, 512, 0, stream>>>(x0s, w0s, coeff, b0, x1s, nullptr);
  gemm_k<9, 8, 0, 8><<<256, 512, 0, stream>>>(x1s, w1s, coeff, b1, x2s, nullptr);
  gemm_k<8, 0, 1, 3><<<96, 512, 0, stream>>>(x2s, w2s, coeff, b2, nullptr, out);
}